// Round 8
// baseline (338.509 us; speedup 1.0000x reference)
//
#include <hip/hip_runtime.h>
#include <hip/hip_bf16.h>
#include <stdint.h>

#define TLEN 480
#define NB 128
#define NC 256

typedef short bf16x8 __attribute__((ext_vector_type(8)));
typedef float f32x4 __attribute__((ext_vector_type(4)));
typedef unsigned int u32x4 __attribute__((ext_vector_type(4)));
typedef unsigned short u16;
typedef unsigned int u32;

__device__ inline u16 f2bf(float f) {   // RNE, used for the A operator (built once)
    union { float f; uint32_t u; } v; v.f = f;
    uint32_t u = v.u;
    return (u16)((u + 0x7fffu + ((u >> 16) & 1u)) >> 16);
}

// pack two fp32 -> (bf16(hi)<<16)|bf16(lo) by truncation: one v_perm_b32
__device__ inline u32 pack2bf(float lo, float hi) {
    return __builtin_amdgcn_perm(__float_as_uint(hi), __float_as_uint(lo), 0x07060302u);
}

// degree-1 LOESS weights; Q compile-time -> full unroll, w[] in registers.
template<int N, int Q>
__device__ __forceinline__ int loess_wT(int t, float* out) {
    int left = t - (Q - 1) / 2;
    if (left < 0) left = 0;
    if (left > N - Q) left = N - Q;
    int right = left + Q - 1;
    int h = (t - left) > (right - t) ? (t - left) : (right - t);
    double w[Q];
    double wsum = 0.0;
    #pragma unroll
    for (int i = 0; i < Q; ++i) {
        double dist = fabs((double)(left + i - t)) / (double)h;
        double u = 1.0 - dist * dist * dist;
        if (u < 0.0) u = 0.0;
        double wv = u * u * u;
        w[i] = wv; wsum += wv;
    }
    #pragma unroll
    for (int i = 0; i < Q; ++i) w[i] /= wsum;
    double xbar = 0.0;
    #pragma unroll
    for (int i = 0; i < Q; ++i) xbar += w[i] * (double)(left + i);
    double var = 0.0;
    #pragma unroll
    for (int i = 0; i < Q; ++i) { double d = (double)(left + i) - xbar; var += w[i] * d * d; }
    if (var > 1e-12) {
        double tb = (double)t - xbar;
        #pragma unroll
        for (int i = 0; i < Q; ++i) {
            double d = (double)(left + i) - xbar;
            out[i] = (float)(w[i] * (1.0 + tb * d / var));
        }
    } else {
        #pragma unroll
        for (int i = 0; i < Q; ++i) out[i] = (float)w[i];
    }
    return left;
}

// Ms dense (34x32), MlpC (480x17 compact), MtC (480x29 compact), w3 (31-tap MA15*MA15*MA3)
__global__ void k_loess(float* Ms, float* w3, float* MlpC, float* MtC) {
    int gid = blockIdx.x * 256 + threadIdx.x;
    if (gid < 34) {
        float wl[7];
        int left = loess_wT<32, 7>(gid - 1, wl);
        float* row = Ms + gid * 32;
        #pragma unroll
        for (int i = 0; i < 32; ++i) row[i] = 0.0f;
        #pragma unroll
        for (int i = 0; i < 7; ++i) row[left + i] = wl[i];
    } else if (gid < 514) {
        int t = gid - 34;
        float wl[17];
        loess_wT<TLEN, 17>(t, wl);
        #pragma unroll
        for (int i = 0; i < 17; ++i) MlpC[t * 17 + i] = wl[i];
    } else if (gid < 994) {
        int t = gid - 514;
        float wl[29];
        loess_wT<TLEN, 29>(t, wl);
        #pragma unroll
        for (int i = 0; i < 29; ++i) MtC[t * 29 + i] = wl[i];
    } else if (gid < 1025) {
        int d = gid - 994;            // 0..30
        int cnt = 0;
        for (int c = 0; c < 3; ++c)
            for (int a = 0; a < 15; ++a) {
                int b = d - a - c;
                if (b >= 0 && b < 15) cnt++;
            }
        w3[d] = (float)((double)cnt / 675.0);
    }
}

// x [B,T,C] fp32 -> xT [B,C,T] bf16 (truncation, same numerics as before).
__global__ __launch_bounds__(256, 2)
void k_T(const float* __restrict__ x, u16* __restrict__ xT) {
    __shared__ u16 Xs[64 * 488];     // 62,464 B
    int b = blockIdx.x;
    int cz = blockIdx.y * 64;
    int tid = threadIdx.x;
    int wq = tid & 15, kkq = tid >> 4;
    const float* xp0 = x + (size_t)b * TLEN * NC + (size_t)(kkq * 4) * NC + cz + wq * 4;
    u32* l32 = (u32*)Xs;
    int lbase = (wq * 4) * 244 + kkq * 2;

    float4 ra[4], rb[4];
    #pragma unroll
    for (int q = 0; q < 4; ++q) ra[q] = *(const float4*)(xp0 + q * NC);
    #pragma unroll
    for (int p = 0; p < 8; ++p) {
        float4* cur = (p & 1) ? rb : ra;
        float4* nxt = (p & 1) ? ra : rb;
        if (p < 7) {
            if (p + 1 < 7 || kkq < 8) {
                const float* xp = xp0 + (size_t)(p + 1) * 64 * NC;
                #pragma unroll
                for (int q = 0; q < 4; ++q) nxt[q] = *(const float4*)(xp + q * NC);
            }
        }
        if (p < 7 || kkq < 8) {
            const float* fl = (const float*)cur;
            int o = lbase + p * 32;
            #pragma unroll
            for (int cc = 0; cc < 4; ++cc) {
                uint2 w;
                w.x = pack2bf(fl[0 * 4 + cc], fl[1 * 4 + cc]);
                w.y = pack2bf(fl[2 * 4 + cc], fl[3 * 4 + cc]);
                *(uint2*)(l32 + o + cc * 244) = w;
            }
        }
    }
    __syncthreads();

    u16* dst = xT + ((size_t)b * NC + cz) * TLEN;
    #pragma unroll
    for (int v = 0; v < 15; ++v) {
        int id = v * 256 + tid;                 // 0..3839 = 64 rows x 60 chunks
        int c = id / 60, j = id - c * 60;
        *(u32x4*)(dst + (size_t)c * TLEN + j * 8) = *(const u32x4*)&Xs[c * 488 + j * 8];
    }
}

// S[t][u] = Ecenter[t][u] - sum_{k<17} MlpC[t][k] * G[slp(t)+k][u]
__global__ void k_S(const float* __restrict__ Ms, const float* __restrict__ w3,
                    const float* __restrict__ MlpC, float* __restrict__ S) {
    int id = blockIdx.x * 256 + threadIdx.x;
    if (id >= TLEN * TLEN) return;
    int t = id / TLEN, u = id - t * TLEN;
    int nu = u / 15, ju = u - nu * 15;
    int slp = t - 8;
    if (slp < 0) slp = 0;
    if (slp > TLEN - 17) slp = TLEN - 17;
    float acc = 0.0f;
    for (int k = 0; k < 17; ++k) {
        int i = slp + k;
        int s_lo = (i - ju + 14) / 15;
        float g = 0.0f;
        #pragma unroll
        for (int ds = 0; ds < 3; ++ds) {
            int s = s_lo + ds;
            int d = s * 15 + ju - i;
            if (s >= 0 && s < 34 && d >= 0 && d <= 30)
                g += Ms[s * 32 + nu] * w3[d];
        }
        acc += MlpC[t * 17 + k] * g;
    }
    float val = -acc;
    if (t % 15 == ju) val += Ms[(1 + t / 15) * 32 + nu];
    S[id] = val;
}

// Fused k_VU + k_A: one 16x16 A-tile per block, U/V never touch global.
//   U[k][u] = Mt[k][u] - sum_j MtC[k][j] S[st_k+j][u]   (u in tile cols)
//   V[t][k] = sum_j MtC[t][j] S[st_t+j][k]              (t in tile rows)
//   A[t][u] = (sum_k V[t][k] U[k][u]) + U[t][u], bf16 out.
// Accumulation orders (j ascending; k ascending via 120-chunks) match the old
// k_VU/k_A exactly -> bit-identical A.  S-band reads are coalesced rows (the
// old k_VU read S columns at stride 1920B: 29 cache lines per thread).
__global__ __launch_bounds__(256)
void k_VUA(const float* __restrict__ MtC, const float* __restrict__ S,
           u16* __restrict__ Abf) {
    __shared__ float Uc[480 * 16];        // 30,720 B, persistent
    __shared__ float Sbuf[7680];          // 30,720 B: Su[480][16], then Schunk[44][121]+Vch[16][121]
    __shared__ float MtCt[16 * 29];       // 1,856 B
    int tid = threadIdx.x;
    int u0 = blockIdx.x * 16, t0 = blockIdx.y * 16;
    int tu = tid & 15, tk = tid >> 4;

    // phase 0: MtC rows for this tile's t-range
    for (int i = tid; i < 16 * 29; i += 256) MtCt[i] = MtC[(t0 + i / 29) * 29 + i % 29];

    // phase 1: S columns u0..u0+15 -> Su[k][tu]
    float* Su = Sbuf;
    #pragma unroll
    for (int it = 0; it < 30; ++it) {
        int k = tk + 16 * it;
        Su[k * 16 + tu] = S[(size_t)k * TLEN + u0 + tu];
    }
    __syncthreads();

    // phase 2: U columns
    #pragma unroll 2
    for (int it = 0; it < 30; ++it) {
        int k = tk + 16 * it;
        int st = k - 14; if (st < 0) st = 0; if (st > TLEN - 29) st = TLEN - 29;
        float acc = 0.0f;
        for (int j = 0; j < 29; ++j) acc += MtC[k * 29 + j] * Su[(st + j) * 16 + tu];
        int u = u0 + tu;
        float mt = (u >= st && u < st + 29) ? MtC[k * 29 + (u - st)] : 0.0f;
        Uc[k * 16 + tu] = mt - acc;
    }
    __syncthreads();   // Su free

    // phase 3: A accumulation over 4 k-chunks of 120
    float* Schunk = Sbuf;                 // [44][121] = 5324 floats
    float* Vch = Sbuf + 44 * 121;         // [16][121] = 1936 floats (total 7260 <= 7680)
    int rlo = t0 - 14; if (rlo < 0) rlo = 0; if (rlo > TLEN - 44) rlo = TLEN - 44;
    float a = 0.0f;
    for (int k0 = 0; k0 < 480; k0 += 120) {
        for (int idx = tid; idx < 44 * 120; idx += 256) {
            int r = idx / 120, c = idx - r * 120;
            Schunk[r * 121 + c] = S[(size_t)(rlo + r) * TLEN + k0 + c];
        }
        __syncthreads();
        {   // V chunk: thread (tt = tid&15, cg = tid>>4) covers cols cg+16i
            int tt = tid & 15, cg = tid >> 4;
            int st = t0 + tt - 14; if (st < 0) st = 0; if (st > TLEN - 29) st = TLEN - 29;
            int ro = st - rlo;
            #pragma unroll
            for (int i = 0; i < 8; ++i) {
                int c = cg + 16 * i;
                if (c < 120) {
                    float v = 0.0f;
                    #pragma unroll
                    for (int j = 0; j < 29; ++j)
                        v += MtCt[tt * 29 + j] * Schunk[(ro + j) * 121 + c];
                    Vch[tt * 121 + c] = v;
                }
            }
        }
        __syncthreads();
        {   // accumulate: thread (tu, tt = tid>>4) owns A[t0+tt][u0+tu]
            int tt = tid >> 4;
            for (int c = 0; c < 120; ++c)
                a += Vch[tt * 121 + c] * Uc[(k0 + c) * 16 + tu];
        }
        __syncthreads();   // next chunk overwrites Schunk/Vch
    }
    int tt = tid >> 4;
    a += Uc[(t0 + tt) * 16 + tu];          // single final add, same value as old U+acc
    Abf[(size_t)(t0 + tt) * TLEN + u0 + tu] = f2bf(a);
}

// Fused GEMM: trend = A @ x_b^T per batch; out1 = trend, out0 = x - trend.
// v8 = v7 structure (pure load->MFMA k-loop, no LDS staging, free-running waves)
// with launch_bounds (256,4): one more block/CU than v7's 3 (LDS 26KB allows 6;
// VGPR budget 128 keeps the compiler's depth-1 prefetch intact).
__global__ __launch_bounds__(256, 4)
void k_gemm(const u16* __restrict__ A, const u16* __restrict__ xT,
            const float* __restrict__ x,
            float* __restrict__ out0, float* __restrict__ out1) {
    __shared__ float T[96 * 68];     // 26,112 B
    int b = blockIdx.x;
    int t0 = blockIdx.y * 96;
    int cz = blockIdx.z * 64;
    int tid = threadIdx.x;
    int wave = tid >> 6, lane = tid & 63;
    int lane15 = lane & 15, quad = lane >> 4;
    int wc = wave & 1, wt = wave >> 1;     // wave tile: 32c x 48t

    const u16* ap0 = xT + ((size_t)b * NC + cz + wc * 32 + lane15) * TLEN + quad * 8;
    const u16* bp0 = A + (size_t)(t0 + wt * 48 + lane15) * TLEN + quad * 8;

    f32x4 acc[2][3] = {};
    bf16x8 acur[2], anxt[2], bcur[3], bnxt[3];
    acur[0] = *(const bf16x8*)ap0;
    acur[1] = *(const bf16x8*)(ap0 + 16 * TLEN);
    #pragma unroll
    for (int j = 0; j < 3; ++j) bcur[j] = *(const bf16x8*)(bp0 + (size_t)j * 16 * TLEN);

    #pragma unroll
    for (int s = 0; s < 15; ++s) {
        bf16x8* ac = (s & 1) ? anxt : acur;
        bf16x8* an = (s & 1) ? acur : anxt;
        bf16x8* bc = (s & 1) ? bnxt : bcur;
        bf16x8* bn = (s & 1) ? bcur : bnxt;
        if (s < 14) {
            int k = (s + 1) * 32;
            an[0] = *(const bf16x8*)(ap0 + k);
            an[1] = *(const bf16x8*)(ap0 + 16 * TLEN + k);
            #pragma unroll
            for (int j = 0; j < 3; ++j)
                bn[j] = *(const bf16x8*)(bp0 + (size_t)j * 16 * TLEN + k);
        }
        #pragma unroll
        for (int j = 0; j < 3; ++j) {
            acc[0][j] = __builtin_amdgcn_mfma_f32_16x16x32_bf16(ac[0], bc[j], acc[0][j], 0, 0, 0);
            acc[1][j] = __builtin_amdgcn_mfma_f32_16x16x32_bf16(ac[1], bc[j], acc[1][j], 0, 0, 0);
        }
    }

    // epilogue: acc -> LDS fp32 [96][68], then full-line nt stores
    #pragma unroll
    for (int i = 0; i < 2; ++i)
        #pragma unroll
        for (int j = 0; j < 3; ++j) {
            int tl = wt * 48 + j * 16 + lane15;
            int cl = wc * 32 + i * 16 + quad * 4;
            *(f32x4*)&T[tl * 68 + cl] = acc[i][j];
        }
    __syncthreads();

    #pragma unroll
    for (int v = 0; v < 6; ++v) {
        int id = v * 256 + tid;
        int tl = id >> 4, c4 = (id & 15) * 4;
        size_t gb = ((size_t)b * TLEN + t0 + tl) * NC + cz + c4;
        f32x4 tv = *(const f32x4*)&T[tl * 68 + c4];
        f32x4 xv = *(const f32x4*)(x + gb);
        __builtin_nontemporal_store(tv, (f32x4*)(out1 + gb));
        __builtin_nontemporal_store(xv - tv, (f32x4*)(out0 + gb));
    }
}

extern "C" void kernel_launch(void* const* d_in, const int* in_sizes, int n_in,
                              void* d_out, int out_size, void* d_ws, size_t ws_size,
                              hipStream_t stream) {
    const float* x = (const float*)d_in[0];
    float* out0 = (float*)d_out;                           // seasonal + resid = x - trend
    float* out1 = (float*)d_out + (size_t)NB * TLEN * NC;  // trend

    char* ws = (char*)d_ws;
    size_t oMs  = 0;                       // 34*32*4 = 4352
    size_t oW3  = oMs + 4352;              // 128
    size_t oLpC = oW3 + 128;               // 480*17*4 = 32640
    size_t oMtC = oLpC + 32640;            // 480*29*4 = 55680
    size_t oS   = oMtC + 55680;            // 921600
    size_t oA   = oS + 921600;             // bf16 460800
    size_t oXT  = oA + 460800;             // bf16 128*256*480*2 = 31,457,280

    float* Ms   = (float*)(ws + oMs);
    float* w3   = (float*)(ws + oW3);
    float* MlpC = (float*)(ws + oLpC);
    float* MtC  = (float*)(ws + oMtC);
    float* S    = (float*)(ws + oS);
    u16*   Abf  = (u16*)(ws + oA);
    u16*   xT   = (u16*)(ws + oXT);

    k_loess<<<5, 256, 0, stream>>>(Ms, w3, MlpC, MtC);
    k_T<<<dim3(NB, 4), 256, 0, stream>>>(x, xT);
    k_S<<<900, 256, 0, stream>>>(Ms, w3, MlpC, S);
    k_VUA<<<dim3(30, 30), 256, 0, stream>>>(MtC, S, Abf);
    k_gemm<<<dim3(NB, 5, 4), 256, 0, stream>>>(Abf, xT, x, out0, out1);
}

// Round 9
// 259.716 us; speedup vs baseline: 1.3034x; 1.3034x over previous
//
#include <hip/hip_runtime.h>
#include <hip/hip_bf16.h>
#include <stdint.h>

#define TLEN 480
#define NB 128
#define NC 256

typedef short bf16x8 __attribute__((ext_vector_type(8)));
typedef float f32x4 __attribute__((ext_vector_type(4)));
typedef unsigned short u16;
typedef unsigned int u32;

__device__ inline u16 f2bf(float f) {   // RNE, used for the A operator (built once)
    union { float f; uint32_t u; } v; v.f = f;
    uint32_t u = v.u;
    return (u16)((u + 0x7fffu + ((u >> 16) & 1u)) >> 16);
}

// pack two fp32 -> (bf16(hi)<<16)|bf16(lo) by truncation: one v_perm_b32
__device__ inline u32 pack2bf(float lo, float hi) {
    return __builtin_amdgcn_perm(__float_as_uint(hi), __float_as_uint(lo), 0x07060302u);
}

// degree-1 LOESS weights; Q compile-time -> full unroll, w[] in registers.
// Arithmetic bit-identical to the original runtime-q version.
template<int N, int Q>
__device__ __forceinline__ int loess_wT(int t, float* out) {
    int left = t - (Q - 1) / 2;
    if (left < 0) left = 0;
    if (left > N - Q) left = N - Q;
    int right = left + Q - 1;
    int h = (t - left) > (right - t) ? (t - left) : (right - t);
    double w[Q];
    double wsum = 0.0;
    #pragma unroll
    for (int i = 0; i < Q; ++i) {
        double dist = fabs((double)(left + i - t)) / (double)h;
        double u = 1.0 - dist * dist * dist;
        if (u < 0.0) u = 0.0;
        double wv = u * u * u;
        w[i] = wv; wsum += wv;
    }
    #pragma unroll
    for (int i = 0; i < Q; ++i) w[i] /= wsum;
    double xbar = 0.0;
    #pragma unroll
    for (int i = 0; i < Q; ++i) xbar += w[i] * (double)(left + i);
    double var = 0.0;
    #pragma unroll
    for (int i = 0; i < Q; ++i) { double d = (double)(left + i) - xbar; var += w[i] * d * d; }
    if (var > 1e-12) {
        double tb = (double)t - xbar;
        #pragma unroll
        for (int i = 0; i < Q; ++i) {
            double d = (double)(left + i) - xbar;
            out[i] = (float)(w[i] * (1.0 + tb * d / var));
        }
    } else {
        #pragma unroll
        for (int i = 0; i < Q; ++i) out[i] = (float)w[i];
    }
    return left;
}

// Ms dense (34x32), MlpC (480x17 compact), MtC (480x29 compact), w3 (31-tap MA15*MA15*MA3)
__global__ void k_loess(float* Ms, float* w3, float* MlpC, float* MtC) {
    int gid = blockIdx.x * 256 + threadIdx.x;
    if (gid < 34) {
        float wl[7];
        int left = loess_wT<32, 7>(gid - 1, wl);
        float* row = Ms + gid * 32;
        #pragma unroll
        for (int i = 0; i < 32; ++i) row[i] = 0.0f;
        #pragma unroll
        for (int i = 0; i < 7; ++i) row[left + i] = wl[i];
    } else if (gid < 514) {
        int t = gid - 34;
        float wl[17];
        loess_wT<TLEN, 17>(t, wl);
        #pragma unroll
        for (int i = 0; i < 17; ++i) MlpC[t * 17 + i] = wl[i];
    } else if (gid < 994) {
        int t = gid - 514;
        float wl[29];
        loess_wT<TLEN, 29>(t, wl);
        #pragma unroll
        for (int i = 0; i < 29; ++i) MtC[t * 29 + i] = wl[i];
    } else if (gid < 1025) {
        int d = gid - 994;            // 0..30
        int cnt = 0;
        for (int c = 0; c < 3; ++c)
            for (int a = 0; a < 15; ++a) {
                int b = d - a - c;
                if (b >= 0 && b < 15) cnt++;
            }
        w3[d] = (float)((double)cnt / 675.0);
    }
}

// S[t][u] = Ecenter[t][u] - sum_{k<17} MlpC[t][k] * G[slp(t)+k][u]
__global__ void k_S(const float* __restrict__ Ms, const float* __restrict__ w3,
                    const float* __restrict__ MlpC, float* __restrict__ S) {
    int id = blockIdx.x * 256 + threadIdx.x;
    if (id >= TLEN * TLEN) return;
    int t = id / TLEN, u = id - t * TLEN;
    int nu = u / 15, ju = u - nu * 15;
    int slp = t - 8;
    if (slp < 0) slp = 0;
    if (slp > TLEN - 17) slp = TLEN - 17;
    float acc = 0.0f;
    for (int k = 0; k < 17; ++k) {
        int i = slp + k;
        int s_lo = (i - ju + 14) / 15;
        float g = 0.0f;
        #pragma unroll
        for (int ds = 0; ds < 3; ++ds) {
            int s = s_lo + ds;
            int d = s * 15 + ju - i;
            if (s >= 0 && s < 34 && d >= 0 && d <= 30)
                g += Ms[s * 32 + nu] * w3[d];
        }
        acc += MlpC[t * 17 + k] * g;
    }
    float val = -acc;
    if (t % 15 == ju) val += Ms[(1 + t / 15) * 32 + nu];
    S[id] = val;
}

// V = Mt @ S (banded 29), U = Mt - V (Mt from compact).  S rows are coalesced
// reads and S (0.92 MB) is L2-resident after k_S.
__global__ void k_VU(const float* __restrict__ MtC, const float* __restrict__ S,
                     float* __restrict__ U, float* __restrict__ V) {
    int id = blockIdx.x * 256 + threadIdx.x;
    if (id >= TLEN * TLEN) return;
    int t = id / TLEN, u = id - t * TLEN;
    int st = t - 14;
    if (st < 0) st = 0;
    if (st > TLEN - 29) st = TLEN - 29;
    float acc = 0.0f;
    for (int k = 0; k < 29; ++k)
        acc += MtC[t * 29 + k] * S[(size_t)(st + k) * TLEN + u];
    float mt = (u >= st && u < st + 29) ? MtC[t * 29 + (u - st)] : 0.0f;
    V[id] = acc;
    U[id] = mt - acc;
}

// A = U + V@U, output bf16 (RNE); 16x16 LDS-tiled fp32 matmul (480^3, tiny)
__global__ void k_A(const float* __restrict__ U, const float* __restrict__ V,
                    u16* __restrict__ Abf) {
    __shared__ float Vs[16][17];
    __shared__ float Us[16][17];
    int tx = threadIdx.x, ty = threadIdx.y;
    int u = blockIdx.x * 16 + tx;
    int t = blockIdx.y * 16 + ty;
    float acc = 0.0f;
    for (int kt = 0; kt < 30; ++kt) {
        Vs[ty][tx] = V[(size_t)t * TLEN + kt * 16 + tx];
        Us[ty][tx] = U[(size_t)(kt * 16 + ty) * TLEN + u];
        __syncthreads();
        #pragma unroll
        for (int e = 0; e < 16; ++e) acc += Vs[ty][e] * Us[e][tx];
        __syncthreads();
    }
    Abf[(size_t)t * TLEN + u] = f2bf(U[(size_t)t * TLEN + u] + acc);
}

// Fused transpose+GEMM: trend = A @ x_b^T per batch; out1 = trend, out0 = x - trend.
//
// v3 structure (empirical best: 80.3 us, total 253.99): grid (b, 5 t-tiles of 96,
// 4 c-quarters of 64).  One block stages ALL of x[b, 0:480, cq*64 +: 64] -> LDS
// bf16 [c][k], row stride 488 u16 (16B-aligned; wave ds_read_b128 conflict-free;
// staging writes 2-way aliased = free per m136).  Staging is a single burst of
// 30 float4 loads/thread (reg double-buffered) -> deep MLP, no dependent round
// trips.  ONE barrier, then barrier-free software-pipelined MFMA (6 MFMA/step
// per wave -- the amortization that beat all smaller tiles), then LDS-transposed
// epilogue: acc -> fp32 [96][68] (aliasing Xs), full-line nt stores (WRITE_SIZE
// pinned at the 126 MB compulsory minimum since v3).
__global__ __launch_bounds__(256, 2)
void k_gemm(const u16* __restrict__ A, const float* __restrict__ x,
            float* __restrict__ out0, float* __restrict__ out1) {
    __shared__ u16 Xs[64 * 488];     // 62,464 B
    int b = blockIdx.x;
    int t0 = blockIdx.y * 96;
    int cz = blockIdx.z * 64;
    int tid = threadIdx.x;
    int wave = tid >> 6, lane = tid & 63;
    int lane15 = lane & 15, quad = lane >> 4;
    int wm = wave & 1, wn = wave >> 1;   // wave tile: 32c x 48t

    // ---- staging: x[b, 0:480, cz:cz+64] -> LDS bf16 [c][488] ----
    int wq  = tid & 15;      // c-quad (4 c's)
    int kkq = tid >> 4;      // k-quad (4 k's); pass covers 64 k
    const float* xp0 = x + (size_t)b * TLEN * NC + (size_t)(kkq * 4) * NC + cz + wq * 4;
    u32* l32 = (u32*)Xs;
    int lbase = (wq * 4) * 244 + kkq * 2;     // u32 offset; +244/channel, +32/pass

    float4 ra[4], rb[4];
    {
        #pragma unroll
        for (int q = 0; q < 4; ++q) ra[q] = *(const float4*)(xp0 + q * NC);
    }
    #pragma unroll
    for (int p = 0; p < 8; ++p) {
        float4* cur = (p & 1) ? rb : ra;
        float4* nxt = (p & 1) ? ra : rb;
        if (p < 7) {   // issue next pass's loads before consuming cur
            if (p + 1 < 7 || kkq < 8) {
                const float* xp = xp0 + (size_t)(p + 1) * 64 * NC;
                #pragma unroll
                for (int q = 0; q < 4; ++q) nxt[q] = *(const float4*)(xp + q * NC);
            }
        }
        if (p < 7 || kkq < 8) {
            const float* fl = (const float*)cur;   // [r*4 + cc], compile-time indexed
            int o = lbase + p * 32;
            #pragma unroll
            for (int cc = 0; cc < 4; ++cc) {
                uint2 w;
                w.x = pack2bf(fl[0 * 4 + cc], fl[1 * 4 + cc]);
                w.y = pack2bf(fl[2 * 4 + cc], fl[3 * 4 + cc]);
                *(uint2*)(l32 + o + cc * 244) = w;
            }
        }
    }
    __syncthreads();   // barrier #1: LDS x-tile complete

    // ---- compute: 15 k-steps, software-pipelined, no barriers ----
    const u16* bp0 = A + (size_t)(t0 + wn * 48 + lane15) * TLEN + quad * 8;
    int arow = (wm * 32 + lane15) * 488 + quad * 8;    // u16 index into Xs

    f32x4 acc[2][3] = {};
    bf16x8 bcur[3], bnxt[3], acur[2], anxt[2];
    #pragma unroll
    for (int j = 0; j < 3; ++j) bcur[j] = *(const bf16x8*)(bp0 + (size_t)j * 16 * TLEN);
    acur[0] = *(const bf16x8*)&Xs[arow];
    acur[1] = *(const bf16x8*)&Xs[arow + 16 * 488];

    #pragma unroll
    for (int s = 0; s < 15; ++s) {
        bf16x8* bc = (s & 1) ? bnxt : bcur;
        bf16x8* bn = (s & 1) ? bcur : bnxt;
        bf16x8* ac = (s & 1) ? anxt : acur;
        bf16x8* an = (s & 1) ? acur : anxt;
        if (s < 14) {
            int k = (s + 1) * 32;
            #pragma unroll
            for (int j = 0; j < 3; ++j)
                bn[j] = *(const bf16x8*)(bp0 + (size_t)j * 16 * TLEN + k);
            an[0] = *(const bf16x8*)&Xs[arow + k];
            an[1] = *(const bf16x8*)&Xs[arow + 16 * 488 + k];
        }
        #pragma unroll
        for (int j = 0; j < 3; ++j) {
            acc[0][j] = __builtin_amdgcn_mfma_f32_16x16x32_bf16(ac[0], bc[j], acc[0][j], 0, 0, 0);
            acc[1][j] = __builtin_amdgcn_mfma_f32_16x16x32_bf16(ac[1], bc[j], acc[1][j], 0, 0, 0);
        }
    }

    __syncthreads();   // barrier #2: everyone done reading Xs; safe to alias

    // ---- epilogue: acc -> LDS fp32 [96][68] (x2 tensors), then line-complete stores ----
    float* T = (float*)Xs;          // trend  [96][68] = 26,112 B
    float* R = T + 96 * 68;         // resid  [96][68]; total 52,224 <= 62,464
    #pragma unroll
    for (int j = 0; j < 3; ++j) {
        int tl = wn * 48 + j * 16 + lane15;
        #pragma unroll
        for (int i = 0; i < 2; ++i) {
            int clb = wm * 32 + i * 16 + quad * 4;
            f32x4 tv = acc[i][j];
            size_t gb = ((size_t)b * TLEN + t0 + tl) * NC + cz + clb;
            f32x4 xv = *(const f32x4*)(x + gb);
            *(f32x4*)&T[tl * 68 + clb] = tv;
            *(f32x4*)&R[tl * 68 + clb] = xv - tv;
        }
    }
    __syncthreads();   // barrier #3

    #pragma unroll
    for (int v = 0; v < 6; ++v) {
        int id = v * 256 + tid;
        int tl = id >> 4, c4 = (id & 15) * 4;
        size_t gb = ((size_t)b * TLEN + t0 + tl) * NC + cz + c4;
        f32x4 tv = *(const f32x4*)&T[tl * 68 + c4];
        f32x4 rv = *(const f32x4*)&R[tl * 68 + c4];
        __builtin_nontemporal_store(tv, (f32x4*)(out1 + gb));
        __builtin_nontemporal_store(rv, (f32x4*)(out0 + gb));
    }
}

extern "C" void kernel_launch(void* const* d_in, const int* in_sizes, int n_in,
                              void* d_out, int out_size, void* d_ws, size_t ws_size,
                              hipStream_t stream) {
    const float* x = (const float*)d_in[0];
    float* out0 = (float*)d_out;                           // seasonal + resid = x - trend
    float* out1 = (float*)d_out + (size_t)NB * TLEN * NC;  // trend

    char* ws = (char*)d_ws;
    size_t oMs  = 0;                       // 34*32*4 = 4352
    size_t oW3  = oMs + 4352;              // 128
    size_t oLpC = oW3 + 128;               // 480*17*4 = 32640
    size_t oMtC = oLpC + 32640;            // 480*29*4 = 55680
    size_t oS   = oMtC + 55680;            // 921600
    size_t oU   = oS + 921600;
    size_t oV   = oU + 921600;
    size_t oA   = oV + 921600;             // bf16 460800

    float* Ms   = (float*)(ws + oMs);
    float* w3   = (float*)(ws + oW3);
    float* MlpC = (float*)(ws + oLpC);
    float* MtC  = (float*)(ws + oMtC);
    float* S    = (float*)(ws + oS);
    float* U    = (float*)(ws + oU);
    float* V    = (float*)(ws + oV);
    u16*   Abf  = (u16*)(ws + oA);

    k_loess<<<5, 256, 0, stream>>>(Ms, w3, MlpC, MtC);
    k_S<<<900, 256, 0, stream>>>(Ms, w3, MlpC, S);
    k_VU<<<900, 256, 0, stream>>>(MtC, S, U, V);
    k_A<<<dim3(30, 30), dim3(16, 16), 0, stream>>>(U, V, Abf);
    k_gemm<<<dim3(NB, 5, 4), 256, 0, stream>>>(Abf, x, out0, out1);
}